// Round 16
// baseline (375.271 us; speedup 1.0000x reference)
//
#include <hip/hip_runtime.h>
#include <math.h>

#define NC1 150
#define HW 196          // 14*14
#define NB 1024
#define DD 32
#define NHD 4
#define HDIM 8
#define KG 2352         // ceil(0.08 * 150*14*14)
#define KCH 10
#define CAP 48          // per-location survivor capacity (avg ~15, +7sd safe)
#define CVS 49          // candV row stride (odd -> conflict-free merge reads)
#define CES 36          // staged CE row stride (16B-aligned rows for float4)
#define KVS 20          // kv row stride in floats (80B rows: b128 writes tile 32 banks)
#define CXS 36          // ctx overlay row stride (16B-aligned; R13-proven layout)

// union LDS (float slots):
//  conv phase : XT[42][196] @0 (8232) | WT[42][152] @8232 (6384)  -> 14616
//  tail phase : candV @0 (196*49=9604) | candC u8 @9604 (196*48 B = 2352 slots)
//               | cnt u32 @11956 (196) | CEs @12152 (150*36=5400) -> 17552
#define UNI_F 17552
#define XT_OFF 0
#define WT_OFF 8232
#define CV_OFF 0
#define CC_OFF 9604
#define CNT_OFF 11956
#define CE_OFF 12152

// ---------------- K0 (merged): pos2d [196,32] + conv-weight transpose ----------------
__global__ void prep2_kernel(const float* __restrict__ cw, float* __restrict__ wtg,
                             float* __restrict__ pos) {
  int i = blockIdx.x * 256 + threadIdx.x;
  if (i < HW * DD) {
    int s = i >> 5, d = i & 31;
    int h = s / 14, w = s % 14;
    int p = (d < 16) ? h : w;
    int dd = (d < 16) ? d : d - 16;
    int j = dd >> 1;
    float dv = expf(-(logf(10000.0f) / 16.0f) * (float)(2 * j));
    float ang = (float)p * dv;
    pos[i] = (dd & 1) ? cosf(ang) : sinf(ang);
    return;
  }
  int j = i - HW * DD;
  if (j < 84 * 152) {
    int k = j / 152, c = j - k * 152;
    wtg[j] = (k < 81 && c < NC1) ? cw[c * 81 + k] : 0.f;
  }
}

// ---------------- K1 (fused, R22 exact): R10 body + 4-way-parallel embed tail ----
__global__ __launch_bounds__(1024, 8) void fused_kernel(const float* __restrict__ x,
                                                        const float* __restrict__ wtg,
                                                        const float* __restrict__ CE,
                                                        const float* __restrict__ pos,
                                                        float* __restrict__ seqo) {
  __shared__ alignas(16) float uni[UNI_F];   // 70208 B
  __shared__ alignas(16) float xs[784];      // 3136 B
  __shared__ unsigned hist[2048];            // 8192 B
  __shared__ unsigned wsum[4];
  __shared__ unsigned s_prefix, s_krem, s_max;   // total ~79.7 KB -> 2 blocks/CU

  int b = blockIdx.x, tid = threadIdx.x;
  int lane = tid & 63, wid = tid >> 6;

  if (tid < 196) ((float4*)xs)[tid] = ((const float4*)(x + (size_t)b * 784))[tid];
  if (tid == 0) { s_prefix = 0u; s_krem = KG; s_max = 0u; }
  __syncthreads();

  int cg = tid / 49;              // ch-group 0..18 (8 ch each, 152 incl 2 pad)
  int g  = tid - cg * 49;         // loc-group 0..48 (4 locs each, 196 exact)
  bool act = (tid < 931);         // 19*49
  float acc[4][8];
#pragma unroll
  for (int i = 0; i < 4; ++i)
#pragma unroll
    for (int j = 0; j < 8; ++j) acc[i][j] = 0.f;

  float* XT = uni + XT_OFF;       // [42][196]
  float* WT = uni + WT_OFF;       // [42][152]

  for (int kb = 0; kb < 84; kb += 42) {
    // build X^T[kk][s]
    for (int i = tid; i < 42 * 196; i += 1024) {
      int kk = i / 196, s = i - kk * 196;
      int k = kb + kk;
      float v = 0.f;
      if (k < 81) {
        int ki = k / 9, kj = k - ki * 9;
        int h = s / 14, w = s - h * 14;
        int r = 2 * h - 4 + ki, c = 2 * w - 4 + kj;
        if (r >= 0 && r < 28 && c >= 0 && c < 28) v = xs[r * 28 + c];
      }
      XT[i] = v;
    }
    // coalesced float4 copy of pre-transposed weights
    for (int i = tid; i < (42 * 152) / 4; i += 1024)
      ((float4*)WT)[i] = ((const float4*)(wtg + kb * 152))[i];
    __syncthreads();
    if (act) {
      const float* xtp = XT + 4 * g;
      const float* wtp = WT + 8 * cg;
#pragma unroll 7
      for (int kk = 0; kk < 42; ++kk) {
        float4 xv = *(const float4*)(xtp + kk * 196);
        float4 w0 = *(const float4*)(wtp + kk * 152);
        float4 w1 = *(const float4*)(wtp + kk * 152 + 4);
        float xa[4] = {xv.x, xv.y, xv.z, xv.w};
        float wa[8] = {w0.x, w0.y, w0.z, w0.w, w1.x, w1.y, w1.z, w1.w};
#pragma unroll
        for (int i = 0; i < 4; ++i)
#pragma unroll
          for (int j = 0; j < 8; ++j) acc[i][j] += xa[i] * wa[j];
      }
    }
    __syncthreads();              // GEMM reads done before next-phase overwrite
  }

  // ---- ReLU in registers (inactive threads already hold zeros) ----
#pragma unroll
  for (int i = 0; i < 4; ++i)
#pragma unroll
    for (int j = 0; j < 8; ++j) acc[i][j] = fmaxf(acc[i][j], 0.f);

  // ---- kth: 3-pass radix select, histograms fed FROM REGISTERS, zero-skip ----
  for (int pass = 0; pass < 3; ++pass) {
    hist[tid] = 0u; hist[tid + 1024] = 0u;
    __syncthreads();
    int shift = (pass == 0) ? 21 : (pass == 1 ? 10 : 0);
    int bits = (pass == 2) ? 10 : 11;
    unsigned mask = (1u << bits) - 1u;
    unsigned pfx = s_prefix;        // snapshot after barrier
    unsigned krem = s_krem;
    int hishift = shift + bits;
    if (pass == 0) {
      unsigned mymax = 0u;
#pragma unroll
      for (int i = 0; i < 4; ++i)
#pragma unroll
        for (int j = 0; j < 8; ++j) {
          unsigned u = __float_as_uint(acc[i][j]);
          mymax = max(mymax, u);
          if (u) atomicAdd(&hist[u >> 21], 1u);
        }
#pragma unroll
      for (int st = 32; st >= 1; st >>= 1)
        mymax = max(mymax, (unsigned)__shfl_xor((int)mymax, st));
      if (lane == 0) atomicMax(&s_max, mymax);
    } else {
#pragma unroll
      for (int i = 0; i < 4; ++i)
#pragma unroll
        for (int j = 0; j < 8; ++j) {
          unsigned u = __float_as_uint(acc[i][j]);
          if (u && (u >> hishift) == pfx) atomicAdd(&hist[(u >> shift) & mask], 1u);
        }
    }
    __syncthreads();
    int segsz = (1 << bits) >> 8;   // 8 or 4
    unsigned segv = 0u, sufv = 0u;
    if (tid < 256) {
      for (int j = 0; j < segsz; ++j) segv += hist[tid * segsz + j];
      sufv = segv;
#pragma unroll
      for (int st = 1; st < 64; st <<= 1) {
        unsigned o = (unsigned)__shfl_down((int)sufv, st);
        if (lane + st < 64) sufv += o;
      }
      if (lane == 0) wsum[wid] = sufv;
    }
    __syncthreads();
    if (tid < 256) {
      unsigned tail = 0u;
      for (int ww = wid + 1; ww < 4; ++ww) tail += wsum[ww];
      sufv += tail;                    // count in segments >= tid
      unsigned above = sufv - segv;
      if (above < krem && sufv >= krem) {   // unique winner
        unsigned cum = above;
        int dsel = tid * segsz;
        for (int d2 = segsz - 1; d2 >= 0; --d2) {
          int dd = tid * segsz + d2;
          if (cum + hist[dd] >= krem) { dsel = dd; break; }
          cum += hist[dd];
        }
        s_prefix = (pfx << bits) | (unsigned)dsel;
        s_krem = krem - cum;
      }
    }
    __syncthreads();
  }

  // ---- survivor compaction: per-location candidate lists in union LDS ----
  float* candV = uni + CV_OFF;
  unsigned char* candC = (unsigned char*)(uni + CC_OFF);
  unsigned* cnt = (unsigned*)(uni + CNT_OFF);
  if (tid < 196) cnt[tid] = 0u;
  __syncthreads();
  float T = __uint_as_float(s_prefix);
  if (act) {
#pragma unroll
    for (int i = 0; i < 4; ++i) {
      int loc = 4 * g + i;
#pragma unroll
      for (int j = 0; j < 8; ++j) {
        float v = acc[i][j];
        if (v >= T && v > 0.f) {      // pad channels (c>=150) are exact zeros
          unsigned slot = atomicAdd(&cnt[loc], 1u);
          if (slot < CAP) {
            candV[loc * CVS + slot] = v;
            candC[loc * CAP + slot] = (unsigned char)(8 * cg + j);
          }
        }
      }
    }
  }
  __syncthreads();

  // ---- merge (tid<196) overlapped with CE staging (tid>=196) ----
  float* CEs = uni + CE_OFF;          // [150][36], float4-aligned rows
  if (tid >= 196) {
    for (int i = tid - 196; i < NC1 * 32; i += 1024 - 196) {
      int c = i >> 5, e = i & 31;
      CEs[c * CES + e] = CE[i];
    }
  }
  if (tid < 196) {
    int loc = tid;
    float tv[KCH]; int tc[KCH];
    unsigned n = cnt[loc]; if (n > CAP) n = CAP;
#pragma unroll
    for (int k = 0; k < KCH; ++k) { tv[k] = 0.f; tc[k] = 0; }
    for (unsigned jj = 0; jj < n; ++jj) {
      float v = candV[loc * CVS + jj];
      int c = candC[loc * CAP + jj];
      // exact reference semantics: order by value desc, tie -> lower channel
      if (v > tv[KCH - 1] || (v == tv[KCH - 1] && c < tc[KCH - 1])) {
        float iv = v; int ic = c;
#pragma unroll
        for (int j = 0; j < KCH; ++j) {
          bool gt = (iv > tv[j]) || (iv == tv[j] && ic < tc[j]);
          float nv = gt ? iv : tv[j]; int nc = gt ? ic : tc[j];
          float ov = gt ? tv[j] : iv; int oc = gt ? tc[j] : ic;
          tv[j] = nv; tc[j] = nc; iv = ov; ic = oc;
        }
      }
    }
    // publish top10 back into this thread's own candV/candC row (reads done)
#pragma unroll
    for (int k = 0; k < KCH; ++k) {
      candV[loc * CVS + k] = tv[k];
      candC[loc * CAP + k] = (unsigned char)tc[k];
    }
  }
  __syncthreads();                    // CEs staged, top10 published

  // ---- embed + PE + write seq: 784 threads, 4 per location (8-elem chunks) ----
  if (tid < 784) {
    int loc = tid >> 2, part = tid & 3;
    float gm = __uint_as_float(s_max);
    float gi = (gm == 0.0f) ? 0.0f : 1.0f / gm;
    float a8[8];
#pragma unroll
    for (int e = 0; e < 8; ++e) a8[e] = 0.f;
#pragma unroll
    for (int k = 0; k < KCH; ++k) {   // unused slots have tv=0 -> no-op
      float v = candV[loc * CVS + k];
      int c = candC[loc * CAP + k];
      const float4* cr = (const float4*)(CEs + c * CES + part * 8);
      float4 c0 = cr[0], c1 = cr[1];
      a8[0] += v * c0.x; a8[1] += v * c0.y; a8[2] += v * c0.z; a8[3] += v * c0.w;
      a8[4] += v * c1.x; a8[5] += v * c1.y; a8[6] += v * c1.z; a8[7] += v * c1.w;
    }
    float* op = seqo + ((size_t)b * HW + loc) * DD + part * 8;
    const float4* pr = (const float4*)(pos + loc * DD + part * 8);
    float4 p0 = pr[0], p1 = pr[1];
    float4 o0 = {a8[0] * gi + p0.x, a8[1] * gi + p0.y, a8[2] * gi + p0.z, a8[3] * gi + p0.w};
    float4 o1 = {a8[4] * gi + p1.x, a8[5] * gi + p1.y, a8[6] * gi + p1.z, a8[7] * gi + p1.w};
    ((float4*)op)[0] = o0; ((float4*)op)[1] = o1;
  }
}

// ---------------- K4 (R25): phase-2 as explicit 4-row register batch ----
// R23/R24 confirmed the latency-window model (unroll 8/16: 200->189->185) but
// the compiler holds VGPR at 48, i.e. only ~2-3 rows of loads in flight; each
// iter still pays most of the ~120cyc LDS latency. R25 forces depth: issue all
// 16 ds_read_b128 for rows t..t+3 back-to-back (named scalars, no arrays ->
// no scratch), then 4 independent dot->exp->fma groups. 196 = 49*4 exactly.
// VGPR est ~95 (<128 -> all 13 waves still launch, 4-per-SIMD worst case).
// Abort-signal: VGPR>128 or dur>=185 -> revert to R24 (unroll 16).
__global__ __launch_bounds__(832, 3) void attn_kernel(const float* __restrict__ seq,
                                                      const float* __restrict__ Wqkv,
                                                      const float* __restrict__ bqkv,
                                                      const float* __restrict__ Wo,
                                                      const float* __restrict__ bo,
                                                      float* __restrict__ outp) {
  __shared__ alignas(16) float kvs[NHD * HW * KVS];  // 62720 B; later ctx[196][36]
  __shared__ alignas(16) float swq[96 * DD];         // 12288 B; later Wo[32][32]
  __shared__ float sbq[96];                          // later bo[32]
  __shared__ unsigned s_kk[NHD];                     // total ~75.4 KB

  int b = blockIdx.x, tid = threadIdx.x;
  int h = tid / HW;               // 0..3 (tid<784)
  int s = tid - h * HW;
  bool act = (tid < NHD * HW);

  // hoist global seq row load: HBM latency hides under LDS weight staging
  float xr[32];
  if (act) {
    const float* row = seq + ((size_t)b * HW + s) * DD;
#pragma unroll
    for (int e = 0; e < 8; ++e) {
      float4 f = ((const float4*)row)[e];
      xr[e * 4 + 0] = f.x; xr[e * 4 + 1] = f.y; xr[e * 4 + 2] = f.z; xr[e * 4 + 3] = f.w;
    }
  }
  for (int i = tid; i < (96 * DD) / 4; i += 832)
    ((float4*)swq)[i] = ((const float4*)Wqkv)[i];
  if (tid < 96) sbq[tid] = bqkv[tid];
  if (tid < NHD) s_kk[tid] = 0u;
  __syncthreads();

  float q[8]; float qq = 0.f;
  if (act) {
    float* kvrow = kvs + (h * HW + s) * KVS;
    // ---- k rows (8 dots), track k.k ----
    {
      float ka[8]; float kk = 0.f;
#pragma unroll
      for (int d = 0; d < 8; ++d) {
        const float* wr = swq + (32 + h * HDIM + d) * DD;
        float acc = sbq[32 + h * HDIM + d];
#pragma unroll
        for (int e = 0; e < DD; e += 4) {
          float4 wv = *(const float4*)(wr + e);
          acc += xr[e + 0] * wv.x + xr[e + 1] * wv.y + xr[e + 2] * wv.z + xr[e + 3] * wv.w;
        }
        ka[d] = acc; kk += acc * acc;
      }
      float4 k0 = {ka[0], ka[1], ka[2], ka[3]}, k1 = {ka[4], ka[5], ka[6], ka[7]};
      ((float4*)kvrow)[0] = k0; ((float4*)kvrow)[1] = k1;
      atomicMax(&s_kk[h], __float_as_uint(kk));
    }
    // ---- v rows ----
    {
      float va[8];
#pragma unroll
      for (int d = 0; d < 8; ++d) {
        const float* wr = swq + (64 + h * HDIM + d) * DD;
        float acc = sbq[64 + h * HDIM + d];
#pragma unroll
        for (int e = 0; e < DD; e += 4) {
          float4 wv = *(const float4*)(wr + e);
          acc += xr[e + 0] * wv.x + xr[e + 1] * wv.y + xr[e + 2] * wv.z + xr[e + 3] * wv.w;
        }
        va[d] = acc;
      }
      float4 v0 = {va[0], va[1], va[2], va[3]}, v1 = {va[4], va[5], va[6], va[7]};
      ((float4*)kvrow)[2] = v0; ((float4*)kvrow)[3] = v1;
    }
    // ---- q row (registers only) ----
#pragma unroll
    for (int d = 0; d < 8; ++d) {
      const float* wr = swq + (h * HDIM + d) * DD;
      float acc = sbq[h * HDIM + d];
#pragma unroll
      for (int e = 0; e < DD; e += 4) {
        float4 wv = *(const float4*)(wr + e);
        acc += xr[e + 0] * wv.x + xr[e + 1] * wv.y + xr[e + 2] * wv.z + xr[e + 3] * wv.w;
      }
      q[d] = acc; qq += acc * acc;
    }
  }
  __syncthreads();

  // ---- phase 2: single-pass softmax, explicit 4-row register batch ----
  float l = 0.f;
  float c0 = 0.f, c1 = 0.f, c2 = 0.f, c3 = 0.f, c4 = 0.f, c5 = 0.f, c6 = 0.f, c7 = 0.f;
  if (act) {
    const float scale = 0.3535533905932738f;
    float kkmax = __uint_as_float(s_kk[h]);
    float negM = -sqrtf(qq * kkmax) * scale;
    const float4* kp = (const float4*)(kvs + (h * HW) * KVS);
    for (int tb = 0; tb < HW; tb += 4) {      // 49 exact batches
      // issue all 16 loads back-to-back (named scalars -> registers)
      float4 a_k0 = kp[0],  a_k1 = kp[1],  a_v0 = kp[2],  a_v1 = kp[3];
      float4 b_k0 = kp[5],  b_k1 = kp[6],  b_v0 = kp[7],  b_v1 = kp[8];
      float4 c_k0 = kp[10], c_k1 = kp[11], c_v0 = kp[12], c_v1 = kp[13];
      float4 d_k0 = kp[15], d_k1 = kp[16], d_v0 = kp[17], d_v1 = kp[18];
      kp += 20;
      // 4 independent dots
      float sa = q[0] * a_k0.x;
      sa = fmaf(q[1], a_k0.y, sa); sa = fmaf(q[2], a_k0.z, sa); sa = fmaf(q[3], a_k0.w, sa);
      sa = fmaf(q[4], a_k1.x, sa); sa = fmaf(q[5], a_k1.y, sa); sa = fmaf(q[6], a_k1.z, sa);
      sa = fmaf(q[7], a_k1.w, sa);
      float sb = q[0] * b_k0.x;
      sb = fmaf(q[1], b_k0.y, sb); sb = fmaf(q[2], b_k0.z, sb); sb = fmaf(q[3], b_k0.w, sb);
      sb = fmaf(q[4], b_k1.x, sb); sb = fmaf(q[5], b_k1.y, sb); sb = fmaf(q[6], b_k1.z, sb);
      sb = fmaf(q[7], b_k1.w, sb);
      float sc = q[0] * c_k0.x;
      sc = fmaf(q[1], c_k0.y, sc); sc = fmaf(q[2], c_k0.z, sc); sc = fmaf(q[3], c_k0.w, sc);
      sc = fmaf(q[4], c_k1.x, sc); sc = fmaf(q[5], c_k1.y, sc); sc = fmaf(q[6], c_k1.z, sc);
      sc = fmaf(q[7], c_k1.w, sc);
      float sd = q[0] * d_k0.x;
      sd = fmaf(q[1], d_k0.y, sd); sd = fmaf(q[2], d_k0.z, sd); sd = fmaf(q[3], d_k0.w, sd);
      sd = fmaf(q[4], d_k1.x, sd); sd = fmaf(q[5], d_k1.y, sd); sd = fmaf(q[6], d_k1.z, sd);
      sd = fmaf(q[7], d_k1.w, sd);
      // 4 independent exps
      float pa = __expf(fmaf(sa, scale, negM));
      float pb = __expf(fmaf(sb, scale, negM));
      float pc = __expf(fmaf(sc, scale, negM));
      float pd = __expf(fmaf(sd, scale, negM));
      l += pa + pb + pc + pd;
      // accumulate (8 chains, 4 adds each)
      c0 = fmaf(pa, a_v0.x, c0); c1 = fmaf(pa, a_v0.y, c1); c2 = fmaf(pa, a_v0.z, c2);
      c3 = fmaf(pa, a_v0.w, c3); c4 = fmaf(pa, a_v1.x, c4); c5 = fmaf(pa, a_v1.y, c5);
      c6 = fmaf(pa, a_v1.z, c6); c7 = fmaf(pa, a_v1.w, c7);
      c0 = fmaf(pb, b_v0.x, c0); c1 = fmaf(pb, b_v0.y, c1); c2 = fmaf(pb, b_v0.z, c2);
      c3 = fmaf(pb, b_v0.w, c3); c4 = fmaf(pb, b_v1.x, c4); c5 = fmaf(pb, b_v1.y, c5);
      c6 = fmaf(pb, b_v1.z, c6); c7 = fmaf(pb, b_v1.w, c7);
      c0 = fmaf(pc, c_v0.x, c0); c1 = fmaf(pc, c_v0.y, c1); c2 = fmaf(pc, c_v0.z, c2);
      c3 = fmaf(pc, c_v0.w, c3); c4 = fmaf(pc, c_v1.x, c4); c5 = fmaf(pc, c_v1.y, c5);
      c6 = fmaf(pc, c_v1.z, c6); c7 = fmaf(pc, c_v1.w, c7);
      c0 = fmaf(pd, d_v0.x, c0); c1 = fmaf(pd, d_v0.y, c1); c2 = fmaf(pd, d_v0.z, c2);
      c3 = fmaf(pd, d_v0.w, c3); c4 = fmaf(pd, d_v1.x, c4); c5 = fmaf(pd, d_v1.y, c5);
      c6 = fmaf(pd, d_v1.z, c6); c7 = fmaf(pd, d_v1.w, c7);
    }
  }
  __syncthreads();                  // all kvs reads done before ctx overlay

  // ---- ctx (normalized) -> LDS overlay [196][36]; stage Wo/bo into dead swq/sbq ----
  float* cx = kvs;
  if (act) {
    float inv = 1.0f / l;
    float* cr = cx + s * CXS + h * HDIM;
    float4 o0 = {c0 * inv, c1 * inv, c2 * inv, c3 * inv};
    float4 o1 = {c4 * inv, c5 * inv, c6 * inv, c7 * inv};
    ((float4*)cr)[0] = o0; ((float4*)cr)[1] = o1;
  }
  for (int i = tid; i < 256; i += 832)            // Wo: 256 float4 = 32x32
    ((float4*)swq)[i] = ((const float4*)Wo)[i];
  if (tid < 32) sbq[tid] = bo[tid];
  __syncthreads();

  // ---- fused out-projection: thread (h,s) -> out[s, 8h..8h+7], in-place ----
  if (act) {
    float4 c[8];
    const float4* crow = (const float4*)(cx + s * CXS);
#pragma unroll
    for (int e = 0; e < 8; ++e) c[e] = crow[e];
    float* op = outp + ((size_t)b * HW + s) * DD + h * HDIM;
#pragma unroll
    for (int dq = 0; dq < 2; ++dq) {
      float4 o;
      float* oo = (float*)&o;
#pragma unroll
      for (int qd = 0; qd < 4; ++qd) {
        int d = h * HDIM + dq * 4 + qd;
        const float4* wr = (const float4*)(swq + d * DD);   // wave-uniform broadcast
        float a2 = sbq[d];
#pragma unroll
        for (int e = 0; e < 8; ++e) {
          float4 w = wr[e];
          a2 += c[e].x * w.x + c[e].y * w.y + c[e].z * w.z + c[e].w * w.w;
        }
        oo[qd] = a2;
      }
      ((float4*)op)[dq] = o;
    }
  }
}

extern "C" void kernel_launch(void* const* d_in, const int* in_sizes, int n_in,
                              void* d_out, int out_size, void* d_ws, size_t ws_size,
                              hipStream_t stream) {
  const float* x  = (const float*)d_in[0];
  const float* cw = (const float*)d_in[1];
  const float* ce = (const float*)d_in[2];
  const float* wq = (const float*)d_in[3];
  const float* bq = (const float*)d_in[4];
  const float* wo = (const float*)d_in[5];
  const float* bo = (const float*)d_in[6];
  float* out = (float*)d_out;
  float* ws  = (float*)d_ws;

  // ws layout (floats): pos [196*32] | wtg [84*152]
  float* pos = ws;
  float* wtg = pos + HW * DD;

  prep2_kernel<<<(HW * DD + 84 * 152 + 255) / 256, 256, 0, stream>>>(cw, wtg, pos);
  fused_kernel<<<NB, 1024, 0, stream>>>(x, wtg, ce, pos, out);       // seq -> d_out
  attn_kernel<<<NB, 832, 0, stream>>>(out, wq, bq, wo, bo, out);     // in-place
}

// Round 17
// 365.536 us; speedup vs baseline: 1.0266x; 1.0266x over previous
//
#include <hip/hip_runtime.h>
#include <math.h>

#define NC1 150
#define HW 196          // 14*14
#define NB 1024
#define DD 32
#define NHD 4
#define HDIM 8
#define KG 2352         // ceil(0.08 * 150*14*14)
#define KCH 10
#define CAP 48          // per-location survivor capacity (avg ~15, +7sd safe)
#define CVS 49          // candV row stride (odd -> conflict-free merge reads)
#define CES 36          // staged CE row stride (16B-aligned rows for float4)
#define KVS 20          // kv row stride in floats (80B rows: b128 writes tile 32 banks)
#define CXS 36          // ctx overlay row stride (16B-aligned; R13-proven layout)

// union LDS (float slots):
//  conv phase : XT[42][196] @0 (8232) | WT[42][152] @8232 (6384)  -> 14616
//  tail phase : candV @0 (196*49=9604) | candC u8 @9604 (196*48 B = 2352 slots)
//               | cnt u32 @11956 (196) | CEs @12152 (150*36=5400) -> 17552
#define UNI_F 17552
#define XT_OFF 0
#define WT_OFF 8232
#define CV_OFF 0
#define CC_OFF 9604
#define CNT_OFF 11956
#define CE_OFF 12152

// ---------------- K0 (merged): pos2d [196,32] + conv-weight transpose ----------------
__global__ void prep2_kernel(const float* __restrict__ cw, float* __restrict__ wtg,
                             float* __restrict__ pos) {
  int i = blockIdx.x * 256 + threadIdx.x;
  if (i < HW * DD) {
    int s = i >> 5, d = i & 31;
    int h = s / 14, w = s % 14;
    int p = (d < 16) ? h : w;
    int dd = (d < 16) ? d : d - 16;
    int j = dd >> 1;
    float dv = expf(-(logf(10000.0f) / 16.0f) * (float)(2 * j));
    float ang = (float)p * dv;
    pos[i] = (dd & 1) ? cosf(ang) : sinf(ang);
    return;
  }
  int j = i - HW * DD;
  if (j < 84 * 152) {
    int k = j / 152, c = j - k * 152;
    wtg[j] = (k < 81 && c < NC1) ? cw[c * 81 + k] : 0.f;
  }
}

// ---------------- K1 (fused, R22 exact): R10 body + 4-way-parallel embed tail ----
__global__ __launch_bounds__(1024, 8) void fused_kernel(const float* __restrict__ x,
                                                        const float* __restrict__ wtg,
                                                        const float* __restrict__ CE,
                                                        const float* __restrict__ pos,
                                                        float* __restrict__ seqo) {
  __shared__ alignas(16) float uni[UNI_F];   // 70208 B
  __shared__ alignas(16) float xs[784];      // 3136 B
  __shared__ unsigned hist[2048];            // 8192 B
  __shared__ unsigned wsum[4];
  __shared__ unsigned s_prefix, s_krem, s_max;   // total ~79.7 KB -> 2 blocks/CU

  int b = blockIdx.x, tid = threadIdx.x;
  int lane = tid & 63, wid = tid >> 6;

  if (tid < 196) ((float4*)xs)[tid] = ((const float4*)(x + (size_t)b * 784))[tid];
  if (tid == 0) { s_prefix = 0u; s_krem = KG; s_max = 0u; }
  __syncthreads();

  int cg = tid / 49;              // ch-group 0..18 (8 ch each, 152 incl 2 pad)
  int g  = tid - cg * 49;         // loc-group 0..48 (4 locs each, 196 exact)
  bool act = (tid < 931);         // 19*49
  float acc[4][8];
#pragma unroll
  for (int i = 0; i < 4; ++i)
#pragma unroll
    for (int j = 0; j < 8; ++j) acc[i][j] = 0.f;

  float* XT = uni + XT_OFF;       // [42][196]
  float* WT = uni + WT_OFF;       // [42][152]

  for (int kb = 0; kb < 84; kb += 42) {
    // build X^T[kk][s]
    for (int i = tid; i < 42 * 196; i += 1024) {
      int kk = i / 196, s = i - kk * 196;
      int k = kb + kk;
      float v = 0.f;
      if (k < 81) {
        int ki = k / 9, kj = k - ki * 9;
        int h = s / 14, w = s - h * 14;
        int r = 2 * h - 4 + ki, c = 2 * w - 4 + kj;
        if (r >= 0 && r < 28 && c >= 0 && c < 28) v = xs[r * 28 + c];
      }
      XT[i] = v;
    }
    // coalesced float4 copy of pre-transposed weights
    for (int i = tid; i < (42 * 152) / 4; i += 1024)
      ((float4*)WT)[i] = ((const float4*)(wtg + kb * 152))[i];
    __syncthreads();
    if (act) {
      const float* xtp = XT + 4 * g;
      const float* wtp = WT + 8 * cg;
#pragma unroll 7
      for (int kk = 0; kk < 42; ++kk) {
        float4 xv = *(const float4*)(xtp + kk * 196);
        float4 w0 = *(const float4*)(wtp + kk * 152);
        float4 w1 = *(const float4*)(wtp + kk * 152 + 4);
        float xa[4] = {xv.x, xv.y, xv.z, xv.w};
        float wa[8] = {w0.x, w0.y, w0.z, w0.w, w1.x, w1.y, w1.z, w1.w};
#pragma unroll
        for (int i = 0; i < 4; ++i)
#pragma unroll
          for (int j = 0; j < 8; ++j) acc[i][j] += xa[i] * wa[j];
      }
    }
    __syncthreads();              // GEMM reads done before next-phase overwrite
  }

  // ---- ReLU in registers (inactive threads already hold zeros) ----
#pragma unroll
  for (int i = 0; i < 4; ++i)
#pragma unroll
    for (int j = 0; j < 8; ++j) acc[i][j] = fmaxf(acc[i][j], 0.f);

  // ---- kth: 3-pass radix select, histograms fed FROM REGISTERS, zero-skip ----
  for (int pass = 0; pass < 3; ++pass) {
    hist[tid] = 0u; hist[tid + 1024] = 0u;
    __syncthreads();
    int shift = (pass == 0) ? 21 : (pass == 1 ? 10 : 0);
    int bits = (pass == 2) ? 10 : 11;
    unsigned mask = (1u << bits) - 1u;
    unsigned pfx = s_prefix;        // snapshot after barrier
    unsigned krem = s_krem;
    int hishift = shift + bits;
    if (pass == 0) {
      unsigned mymax = 0u;
#pragma unroll
      for (int i = 0; i < 4; ++i)
#pragma unroll
        for (int j = 0; j < 8; ++j) {
          unsigned u = __float_as_uint(acc[i][j]);
          mymax = max(mymax, u);
          if (u) atomicAdd(&hist[u >> 21], 1u);
        }
#pragma unroll
      for (int st = 32; st >= 1; st >>= 1)
        mymax = max(mymax, (unsigned)__shfl_xor((int)mymax, st));
      if (lane == 0) atomicMax(&s_max, mymax);
    } else {
#pragma unroll
      for (int i = 0; i < 4; ++i)
#pragma unroll
        for (int j = 0; j < 8; ++j) {
          unsigned u = __float_as_uint(acc[i][j]);
          if (u && (u >> hishift) == pfx) atomicAdd(&hist[(u >> shift) & mask], 1u);
        }
    }
    __syncthreads();
    int segsz = (1 << bits) >> 8;   // 8 or 4
    unsigned segv = 0u, sufv = 0u;
    if (tid < 256) {
      for (int j = 0; j < segsz; ++j) segv += hist[tid * segsz + j];
      sufv = segv;
#pragma unroll
      for (int st = 1; st < 64; st <<= 1) {
        unsigned o = (unsigned)__shfl_down((int)sufv, st);
        if (lane + st < 64) sufv += o;
      }
      if (lane == 0) wsum[wid] = sufv;
    }
    __syncthreads();
    if (tid < 256) {
      unsigned tail = 0u;
      for (int ww = wid + 1; ww < 4; ++ww) tail += wsum[ww];
      sufv += tail;                    // count in segments >= tid
      unsigned above = sufv - segv;
      if (above < krem && sufv >= krem) {   // unique winner
        unsigned cum = above;
        int dsel = tid * segsz;
        for (int d2 = segsz - 1; d2 >= 0; --d2) {
          int dd = tid * segsz + d2;
          if (cum + hist[dd] >= krem) { dsel = dd; break; }
          cum += hist[dd];
        }
        s_prefix = (pfx << bits) | (unsigned)dsel;
        s_krem = krem - cum;
      }
    }
    __syncthreads();
  }

  // ---- survivor compaction: per-location candidate lists in union LDS ----
  float* candV = uni + CV_OFF;
  unsigned char* candC = (unsigned char*)(uni + CC_OFF);
  unsigned* cnt = (unsigned*)(uni + CNT_OFF);
  if (tid < 196) cnt[tid] = 0u;
  __syncthreads();
  float T = __uint_as_float(s_prefix);
  if (act) {
#pragma unroll
    for (int i = 0; i < 4; ++i) {
      int loc = 4 * g + i;
#pragma unroll
      for (int j = 0; j < 8; ++j) {
        float v = acc[i][j];
        if (v >= T && v > 0.f) {      // pad channels (c>=150) are exact zeros
          unsigned slot = atomicAdd(&cnt[loc], 1u);
          if (slot < CAP) {
            candV[loc * CVS + slot] = v;
            candC[loc * CAP + slot] = (unsigned char)(8 * cg + j);
          }
        }
      }
    }
  }
  __syncthreads();

  // ---- merge (tid<196) overlapped with CE staging (tid>=196) ----
  float* CEs = uni + CE_OFF;          // [150][36], float4-aligned rows
  if (tid >= 196) {
    for (int i = tid - 196; i < NC1 * 32; i += 1024 - 196) {
      int c = i >> 5, e = i & 31;
      CEs[c * CES + e] = CE[i];
    }
  }
  if (tid < 196) {
    int loc = tid;
    float tv[KCH]; int tc[KCH];
    unsigned n = cnt[loc]; if (n > CAP) n = CAP;
#pragma unroll
    for (int k = 0; k < KCH; ++k) { tv[k] = 0.f; tc[k] = 0; }
    for (unsigned jj = 0; jj < n; ++jj) {
      float v = candV[loc * CVS + jj];
      int c = candC[loc * CAP + jj];
      // exact reference semantics: order by value desc, tie -> lower channel
      if (v > tv[KCH - 1] || (v == tv[KCH - 1] && c < tc[KCH - 1])) {
        float iv = v; int ic = c;
#pragma unroll
        for (int j = 0; j < KCH; ++j) {
          bool gt = (iv > tv[j]) || (iv == tv[j] && ic < tc[j]);
          float nv = gt ? iv : tv[j]; int nc = gt ? ic : tc[j];
          float ov = gt ? tv[j] : iv; int oc = gt ? tc[j] : ic;
          tv[j] = nv; tc[j] = nc; iv = ov; ic = oc;
        }
      }
    }
    // publish top10 back into this thread's own candV/candC row (reads done)
#pragma unroll
    for (int k = 0; k < KCH; ++k) {
      candV[loc * CVS + k] = tv[k];
      candC[loc * CAP + k] = (unsigned char)tc[k];
    }
  }
  __syncthreads();                    // CEs staged, top10 published

  // ---- embed + PE + write seq: 784 threads, 4 per location (8-elem chunks) ----
  if (tid < 784) {
    int loc = tid >> 2, part = tid & 3;
    float gm = __uint_as_float(s_max);
    float gi = (gm == 0.0f) ? 0.0f : 1.0f / gm;
    float a8[8];
#pragma unroll
    for (int e = 0; e < 8; ++e) a8[e] = 0.f;
#pragma unroll
    for (int k = 0; k < KCH; ++k) {   // unused slots have tv=0 -> no-op
      float v = candV[loc * CVS + k];
      int c = candC[loc * CAP + k];
      const float4* cr = (const float4*)(CEs + c * CES + part * 8);
      float4 c0 = cr[0], c1 = cr[1];
      a8[0] += v * c0.x; a8[1] += v * c0.y; a8[2] += v * c0.z; a8[3] += v * c0.w;
      a8[4] += v * c1.x; a8[5] += v * c1.y; a8[6] += v * c1.z; a8[7] += v * c1.w;
    }
    float* op = seqo + ((size_t)b * HW + loc) * DD + part * 8;
    const float4* pr = (const float4*)(pos + loc * DD + part * 8);
    float4 p0 = pr[0], p1 = pr[1];
    float4 o0 = {a8[0] * gi + p0.x, a8[1] * gi + p0.y, a8[2] * gi + p0.z, a8[3] * gi + p0.w};
    float4 o1 = {a8[4] * gi + p1.x, a8[5] * gi + p1.y, a8[6] * gi + p1.z, a8[7] * gi + p1.w};
    ((float4*)op)[0] = o0; ((float4*)op)[1] = o1;
  }
}

// ---------------- K4 (R26 = R24 exact): MHA + fused outproj, phase-2 unroll 16 ----
// R25 retro: explicit 4-row batch spilled (VGPR 64 + 54MB scratch writes, 196us)
// -- pre-registered abort-signal fired; depth-forcing refuted in both directions
// (compiler won't spend regs voluntarily, forcing spills). R24's unroll-16
// compiler schedule is the measured optimum: 185us, VGPR 48, no spill.
__global__ __launch_bounds__(832, 3) void attn_kernel(const float* __restrict__ seq,
                                                      const float* __restrict__ Wqkv,
                                                      const float* __restrict__ bqkv,
                                                      const float* __restrict__ Wo,
                                                      const float* __restrict__ bo,
                                                      float* __restrict__ outp) {
  __shared__ alignas(16) float kvs[NHD * HW * KVS];  // 62720 B; later ctx[196][36]
  __shared__ alignas(16) float swq[96 * DD];         // 12288 B; later Wo[32][32]
  __shared__ float sbq[96];                          // later bo[32]
  __shared__ unsigned s_kk[NHD];                     // total ~75.4 KB

  int b = blockIdx.x, tid = threadIdx.x;
  int h = tid / HW;               // 0..3 (tid<784)
  int s = tid - h * HW;
  bool act = (tid < NHD * HW);

  // hoist global seq row load: HBM latency hides under LDS weight staging
  float xr[32];
  if (act) {
    const float* row = seq + ((size_t)b * HW + s) * DD;
#pragma unroll
    for (int e = 0; e < 8; ++e) {
      float4 f = ((const float4*)row)[e];
      xr[e * 4 + 0] = f.x; xr[e * 4 + 1] = f.y; xr[e * 4 + 2] = f.z; xr[e * 4 + 3] = f.w;
    }
  }
  for (int i = tid; i < (96 * DD) / 4; i += 832)
    ((float4*)swq)[i] = ((const float4*)Wqkv)[i];
  if (tid < 96) sbq[tid] = bqkv[tid];
  if (tid < NHD) s_kk[tid] = 0u;
  __syncthreads();

  float q[8]; float qq = 0.f;
  if (act) {
    float* kvrow = kvs + (h * HW + s) * KVS;
    // ---- k rows (8 dots), track k.k ----
    {
      float ka[8]; float kk = 0.f;
#pragma unroll
      for (int d = 0; d < 8; ++d) {
        const float* wr = swq + (32 + h * HDIM + d) * DD;
        float acc = sbq[32 + h * HDIM + d];
#pragma unroll
        for (int e = 0; e < DD; e += 4) {
          float4 wv = *(const float4*)(wr + e);
          acc += xr[e + 0] * wv.x + xr[e + 1] * wv.y + xr[e + 2] * wv.z + xr[e + 3] * wv.w;
        }
        ka[d] = acc; kk += acc * acc;
      }
      float4 k0 = {ka[0], ka[1], ka[2], ka[3]}, k1 = {ka[4], ka[5], ka[6], ka[7]};
      ((float4*)kvrow)[0] = k0; ((float4*)kvrow)[1] = k1;
      atomicMax(&s_kk[h], __float_as_uint(kk));
    }
    // ---- v rows ----
    {
      float va[8];
#pragma unroll
      for (int d = 0; d < 8; ++d) {
        const float* wr = swq + (64 + h * HDIM + d) * DD;
        float acc = sbq[64 + h * HDIM + d];
#pragma unroll
        for (int e = 0; e < DD; e += 4) {
          float4 wv = *(const float4*)(wr + e);
          acc += xr[e + 0] * wv.x + xr[e + 1] * wv.y + xr[e + 2] * wv.z + xr[e + 3] * wv.w;
        }
        va[d] = acc;
      }
      float4 v0 = {va[0], va[1], va[2], va[3]}, v1 = {va[4], va[5], va[6], va[7]};
      ((float4*)kvrow)[2] = v0; ((float4*)kvrow)[3] = v1;
    }
    // ---- q row (registers only) ----
#pragma unroll
    for (int d = 0; d < 8; ++d) {
      const float* wr = swq + (h * HDIM + d) * DD;
      float acc = sbq[h * HDIM + d];
#pragma unroll
      for (int e = 0; e < DD; e += 4) {
        float4 wv = *(const float4*)(wr + e);
        acc += xr[e + 0] * wv.x + xr[e + 1] * wv.y + xr[e + 2] * wv.z + xr[e + 3] * wv.w;
      }
      q[d] = acc; qq += acc * acc;
    }
  }
  __syncthreads();

  // ---- phase 2: single-pass softmax (__expf), unroll 16 ----
  float l = 0.f;
  float c0 = 0.f, c1 = 0.f, c2 = 0.f, c3 = 0.f, c4 = 0.f, c5 = 0.f, c6 = 0.f, c7 = 0.f;
  if (act) {
    const float scale = 0.3535533905932738f;
    float kkmax = __uint_as_float(s_kk[h]);
    float negM = -sqrtf(qq * kkmax) * scale;
    const float4* kp = (const float4*)(kvs + (h * HW) * KVS);
#pragma unroll 16
    for (int t = 0; t < HW; ++t) {
      float4 k0 = kp[0], k1 = kp[1], v0 = kp[2], v1 = kp[3];
      kp += 5;                       // 80B row
      float sc = q[0] * k0.x;
      sc = fmaf(q[1], k0.y, sc); sc = fmaf(q[2], k0.z, sc); sc = fmaf(q[3], k0.w, sc);
      sc = fmaf(q[4], k1.x, sc); sc = fmaf(q[5], k1.y, sc); sc = fmaf(q[6], k1.z, sc);
      sc = fmaf(q[7], k1.w, sc);
      float p = __expf(fmaf(sc, scale, negM));
      l += p;
      c0 = fmaf(p, v0.x, c0); c1 = fmaf(p, v0.y, c1); c2 = fmaf(p, v0.z, c2);
      c3 = fmaf(p, v0.w, c3); c4 = fmaf(p, v1.x, c4); c5 = fmaf(p, v1.y, c5);
      c6 = fmaf(p, v1.z, c6); c7 = fmaf(p, v1.w, c7);
    }
  }
  __syncthreads();                  // all kvs reads done before ctx overlay

  // ---- ctx (normalized) -> LDS overlay [196][36]; stage Wo/bo into dead swq/sbq ----
  float* cx = kvs;
  if (act) {
    float inv = 1.0f / l;
    float* cr = cx + s * CXS + h * HDIM;
    float4 o0 = {c0 * inv, c1 * inv, c2 * inv, c3 * inv};
    float4 o1 = {c4 * inv, c5 * inv, c6 * inv, c7 * inv};
    ((float4*)cr)[0] = o0; ((float4*)cr)[1] = o1;
  }
  for (int i = tid; i < 256; i += 832)            // Wo: 256 float4 = 32x32
    ((float4*)swq)[i] = ((const float4*)Wo)[i];
  if (tid < 32) sbq[tid] = bo[tid];
  __syncthreads();

  // ---- fused out-projection: thread (h,s) -> out[s, 8h..8h+7], in-place ----
  if (act) {
    float4 c[8];
    const float4* crow = (const float4*)(cx + s * CXS);
#pragma unroll
    for (int e = 0; e < 8; ++e) c[e] = crow[e];
    float* op = outp + ((size_t)b * HW + s) * DD + h * HDIM;
#pragma unroll
    for (int dq = 0; dq < 2; ++dq) {
      float4 o;
      float* oo = (float*)&o;
#pragma unroll
      for (int qd = 0; qd < 4; ++qd) {
        int d = h * HDIM + dq * 4 + qd;
        const float4* wr = (const float4*)(swq + d * DD);   // wave-uniform broadcast
        float a2 = sbq[d];
#pragma unroll
        for (int e = 0; e < 8; ++e) {
          float4 w = wr[e];
          a2 += c[e].x * w.x + c[e].y * w.y + c[e].z * w.z + c[e].w * w.w;
        }
        oo[qd] = a2;
      }
      ((float4*)op)[dq] = o;
    }
  }
}

extern "C" void kernel_launch(void* const* d_in, const int* in_sizes, int n_in,
                              void* d_out, int out_size, void* d_ws, size_t ws_size,
                              hipStream_t stream) {
  const float* x  = (const float*)d_in[0];
  const float* cw = (const float*)d_in[1];
  const float* ce = (const float*)d_in[2];
  const float* wq = (const float*)d_in[3];
  const float* bq = (const float*)d_in[4];
  const float* wo = (const float*)d_in[5];
  const float* bo = (const float*)d_in[6];
  float* out = (float*)d_out;
  float* ws  = (float*)d_ws;

  // ws layout (floats): pos [196*32] | wtg [84*152]
  float* pos = ws;
  float* wtg = pos + HW * DD;

  prep2_kernel<<<(HW * DD + 84 * 152 + 255) / 256, 256, 0, stream>>>(cw, wtg, pos);
  fused_kernel<<<NB, 1024, 0, stream>>>(x, wtg, ce, pos, out);       // seq -> d_out
  attn_kernel<<<NB, 832, 0, stream>>>(out, wq, bq, wo, bo, out);     // in-place
}